// Round 8
// baseline (92.030 us; speedup 1.0000x reference)
//
#include <hip/hip_runtime.h>
#include <math.h>

#define CC 128
#define TWO_C 256
#define NT 8
#define HH 64
#define DD 16

typedef short bf16x8 __attribute__((ext_vector_type(8)));
typedef float f32x4 __attribute__((ext_vector_type(4)));

static __device__ __forceinline__ unsigned short f2bf_rne(float f) {
    union { float f; unsigned int u; } v; v.f = f;
    unsigned int r = (v.u + 0x7fffu + ((v.u >> 16) & 1u)) >> 16;
    return (unsigned short)r;
}
static __device__ __forceinline__ unsigned int pkbf(float a, float b) {
    unsigned int ua = __float_as_uint(a) + 0x8000u;
    unsigned int ub = __float_as_uint(b) + 0x8000u;
    return (ua >> 16) | (ub & 0xffff0000u);
}
// async global->LDS, 16B per lane; LDS dest wave-uniform base + lane*16
static __device__ __forceinline__ void glds16(const void* g, void* l) {
    __builtin_amdgcn_global_load_lds(
        (const __attribute__((address_space(1))) void*)g,
        (__attribute__((address_space(3))) void*)l, 16, 0, 0);
}

// ---------------- P0: weight pack + s1/c1 + x->bf16 + per-node S,Q + hist partials
// Segments by global tid:
//   [0,16384)            W1p pack (gamma-folded)
//   [16384,17408)        W2p pack
//   [17408,17920)        s1,c1
//   [17920,histBase)     xb conversion + per-node S,Q   (absent in fallback)
//   [histBase, ...)      edge-type histogram -> per-block partial rows (plain stores)
__global__ __launch_bounds__(256) void pack_kernel(
    const float* __restrict__ W1, const float* __restrict__ W2,
    const float* __restrict__ gamma, const float* __restrict__ beta,
    const float* __restrict__ b1, const float* __restrict__ x,
    unsigned short* __restrict__ W1p, unsigned short* __restrict__ W2p,
    float* __restrict__ s1g, float* __restrict__ c1g,
    unsigned short* __restrict__ xb, float2* __restrict__ SQ, int Nnodes,
    const int* __restrict__ et, int* __restrict__ partial, int histBase, int E)
{
    const int tid = blockIdx.x * 256 + threadIdx.x;

    if (tid < 16384) {
        int l = tid & 63, kt = (tid >> 6) & 7, nt = (tid >> 9) & 3, t = tid >> 11;
        int n = nt * 16 + (l & 15);
        int k0 = kt * 32 + (l >> 4) * 8;
        #pragma unroll
        for (int j = 0; j < 8; ++j) {
            int k = k0 + j;
            float v = gamma[t * TWO_C + k] * W1[(size_t)t * TWO_C * HH + (size_t)k * HH + n];
            W1p[tid * 8 + j] = f2bf_rne(v);
        }
    } else if (tid < 17408) {
        int s = tid - 16384;
        int l = s & 63, kt = (s >> 6) & 1, t = s >> 7;
        int n = l & 15;
        int k0 = kt * 32 + (l >> 4) * 8;
        #pragma unroll
        for (int j = 0; j < 8; ++j)
            W2p[s * 8 + j] = f2bf_rne(W2[(size_t)t * HH * DD + (size_t)(k0 + j) * DD + n]);
    } else if (tid < 17920) {
        int s = tid - 17408;
        int t = s >> 6, n = s & 63;
        float sa = 0.f, ca = 0.f;
        for (int k = 0; k < TWO_C; ++k) {
            float wv = W1[(size_t)t * TWO_C * HH + (size_t)k * HH + n];
            sa = fmaf(gamma[t * TWO_C + k], wv, sa);
            ca = fmaf(beta[t * TWO_C + k], wv, ca);
        }
        s1g[s] = sa;
        c1g[s] = ca + b1[s];
    } else if (tid < histBase) {
        // 16 lanes per node: xb conversion + per-node S,Q (f32-exact moments)
        int idx = tid - 17920;
        int v = idx >> 4;
        if (v < Nnodes) {
            int ll = idx & 15;
            int base = idx * 8;          // == v*128 + ll*8
            float4 p = *(const float4*)(x + base);
            float4 q = *(const float4*)(x + base + 4);
            uint4 u;
            u.x = pkbf(p.x, p.y); u.y = pkbf(p.z, p.w);
            u.z = pkbf(q.x, q.y); u.w = pkbf(q.z, q.w);
            *(uint4*)(xb + base) = u;
            float s  = p.x + p.y + p.z + p.w + q.x + q.y + q.z + q.w;
            float sq = p.x*p.x + p.y*p.y + p.z*p.z + p.w*p.w
                     + q.x*q.x + q.y*q.y + q.z*q.z + q.w*q.w;
            #pragma unroll
            for (int off = 1; off < 16; off <<= 1) {
                s  += __shfl_xor(s, off);
                sq += __shfl_xor(sq, off);
            }
            if (ll == 0) SQ[v] = make_float2(s, sq);
        }
    }

    // ---- histogram partials (uniform control flow; most blocks contribute 0) ----
    __shared__ int lh[NT];
    if (threadIdx.x < NT) lh[threadIdx.x] = 0;
    __syncthreads();
    int hi = tid - histBase;
    if (hi >= 0) {
        int i0 = hi * 4;
        if (i0 + 3 < E) {
            int4 tv = *(const int4*)(et + i0);
            atomicAdd(&lh[tv.x], 1); atomicAdd(&lh[tv.y], 1);
            atomicAdd(&lh[tv.z], 1); atomicAdd(&lh[tv.w], 1);
        } else {
            #pragma unroll
            for (int j = 0; j < 4; ++j)
                if (i0 + j < E) atomicAdd(&lh[et[i0 + j]], 1);
        }
    }
    __syncthreads();
    if (threadIdx.x < NT) partial[blockIdx.x * NT + threadIdx.x] = lh[threadIdx.x];
}

// ---------------- P2: reduce partials -> counts, padded exclusive scan -> po, cursor
__global__ __launch_bounds__(256) void scan_kernel(const int* __restrict__ partial,
                                                   int nblk,
                                                   int* __restrict__ counts,
                                                   int* __restrict__ po,
                                                   int* __restrict__ cursor)
{
    int a0=0,a1=0,a2=0,a3=0,a4=0,a5=0,a6=0,a7=0;
    for (int b = threadIdx.x; b < nblk; b += 256) {
        const int4* p = (const int4*)(partial + b * NT);
        int4 u = p[0], v = p[1];
        a0 += u.x; a1 += u.y; a2 += u.z; a3 += u.w;
        a4 += v.x; a5 += v.y; a6 += v.z; a7 += v.w;
    }
    __shared__ int sh[NT];
    if (threadIdx.x < NT) sh[threadIdx.x] = 0;
    __syncthreads();
    atomicAdd(&sh[0], a0); atomicAdd(&sh[1], a1);
    atomicAdd(&sh[2], a2); atomicAdd(&sh[3], a3);
    atomicAdd(&sh[4], a4); atomicAdd(&sh[5], a5);
    atomicAdd(&sh[6], a6); atomicAdd(&sh[7], a7);
    __syncthreads();
    if (threadIdx.x == 0) {
        int acc = 0;
        for (int t = 0; t < NT; ++t) {
            counts[t] = sh[t];
            po[t] = acc;
            cursor[t] = acc;
            acc += ((sh[t] + 63) >> 6) << 6;
        }
        po[NT] = acc;
    }
}

// ---------------- P3: scatter ----------------
__global__ __launch_bounds__(256) void scatter_kernel(const int* __restrict__ et,
                                                      const int* __restrict__ ei,
                                                      int* __restrict__ cursor,
                                                      int* __restrict__ sorted,
                                                      int* __restrict__ srow,
                                                      int* __restrict__ scol,
                                                      int* __restrict__ inv,
                                                      int E, int write_inv)
{
    __shared__ int lh[NT], lbase[NT];
    if (threadIdx.x < NT) lh[threadIdx.x] = 0;
    __syncthreads();
    int i0 = (blockIdx.x * 256 + threadIdx.x) * 4;
    int tl[4], rk[4];
    #pragma unroll
    for (int j = 0; j < 4; ++j) {
        int i = i0 + j;
        if (i < E) { tl[j] = et[i]; rk[j] = atomicAdd(&lh[tl[j]], 1); }
    }
    __syncthreads();
    if (threadIdx.x < NT)
        lbase[threadIdx.x] = lh[threadIdx.x] ? atomicAdd(&cursor[threadIdx.x], lh[threadIdx.x]) : 0;
    __syncthreads();
    #pragma unroll
    for (int j = 0; j < 4; ++j) {
        int i = i0 + j;
        if (i < E) {
            int slot = lbase[tl[j]] + rk[j];
            sorted[slot] = i;
            srow[slot] = ei[i];
            scol[slot] = ei[E + i];
            if (write_inv) inv[i] = slot;
        }
    }
}

// LDS map: [0,16384) xhat half-tile bf16 [64][256B] XOR-swz; h1 [64][144B] aliased
//          [16384,16896) stats float2[64]; [16896,17152) sid; [17152,17408) rbuf; [17408,17664) cbuf
#define XHAT_OFF 0
#define H1_OFF   0
#define STATS_OFF 16384
#define SID_OFF   16896
#define RB_OFF    17152
#define CB_OFF    17408
#define LDS_BYTES 17664

// ---------------- P5 (full): glds staging, precomputed moments ----------------
template <int TMP>
__global__ __launch_bounds__(256, 8) void sheaf_main_full(
    const unsigned short* __restrict__ xb, const float* __restrict__ b2,
    const unsigned short* __restrict__ W1p, const unsigned short* __restrict__ W2p,
    const float* __restrict__ s1g, const float* __restrict__ c1g,
    const float2* __restrict__ SQ,
    const int* __restrict__ po, const int* __restrict__ counts,
    const int* __restrict__ sorted, const int* __restrict__ srow,
    const int* __restrict__ scol,
    float* __restrict__ dst)
{
    __shared__ __align__(16) unsigned char lds[LDS_BYTES];
    const int base = blockIdx.x * 64;
    if (base >= po[NT]) return;
    int t = 0;
    while (base >= po[t + 1]) ++t;

    const int tid = threadIdx.x;
    const int w = tid >> 6, lane = tid & 63;
    const int lg = lane >> 4, ll = lane & 15;

    int* sid  = (int*)(lds + SID_OFF);
    int* rbuf = (int*)(lds + RB_OFF);
    int* cbuf = (int*)(lds + CB_OFF);
    float2* stats = (float2*)(lds + STATS_OFF);

    if (tid < 64) {
        int slot = base + tid;
        int lim = po[t] + counts[t];
        int src = slot < lim ? slot : po[t];      // padding: replicate bucket head
        rbuf[tid] = srow[src];
        cbuf[tid] = scol[src];
        if (!TMP) sid[tid] = sorted[src];
    }
    __syncthreads();

    // ---- stage half A (x[row]) via global_load_lds, source pre-swizzled ----
    #pragma unroll
    for (int i = 0; i < 4; ++i) {
        const int el = w * 16 + i * 4 + lg;
        const unsigned short* src = xb + (size_t)rbuf[el] * CC + ((ll ^ (el & 7)) * 8);
        glds16(src, lds + XHAT_OFF + (w * 16 + i * 4) * 256);
    }
    // ---- LN moments from per-node S,Q (overlaps glds latency) ----
    if (tid < 64) {
        float2 a = SQ[rbuf[tid]];
        float2 b = SQ[cbuf[tid]];
        float mu  = (a.x + b.x) * (1.0f / TWO_C);
        float var = (a.y + b.y) * (1.0f / TWO_C) - mu * mu;
        stats[tid] = make_float2(mu, rsqrtf(var + 1e-5f));
    }
    __syncthreads();   // drains vmcnt: A staged, stats ready

    // ---- GEMM1 half A (k 0..127) ----
    f32x4 acc[4];
    #pragma unroll
    for (int mt = 0; mt < 4; ++mt) acc[mt] = (f32x4){0.f, 0.f, 0.f, 0.f};
    const bf16x8* Bp = (const bf16x8*)W1p + (size_t)((t * 4 + w) * 8) * 64 + lane;
    #pragma unroll
    for (int kt = 0; kt < 4; ++kt) {
        bf16x8 bfrag = Bp[kt * 64];
        #pragma unroll
        for (int mt = 0; mt < 4; ++mt) {
            int row = mt * 16 + ll;
            bf16x8 afrag = *(const bf16x8*)(lds + XHAT_OFF + row * 256 +
                                            ((kt * 64 + lg * 16) ^ ((row & 7) << 4)));
            acc[mt] = __builtin_amdgcn_mfma_f32_16x16x32_bf16(afrag, bfrag, acc[mt], 0, 0, 0);
        }
    }
    __syncthreads();   // all waves done reading A

    // ---- stage half B (x[col]) ----
    #pragma unroll
    for (int i = 0; i < 4; ++i) {
        const int el = w * 16 + i * 4 + lg;
        const unsigned short* src = xb + (size_t)cbuf[el] * CC + ((ll ^ (el & 7)) * 8);
        glds16(src, lds + XHAT_OFF + (w * 16 + i * 4) * 256);
    }
    __syncthreads();   // B staged

    // ---- GEMM1 half B (k 128..255) ----
    #pragma unroll
    for (int kt = 0; kt < 4; ++kt) {
        bf16x8 bfrag = Bp[(4 + kt) * 64];
        #pragma unroll
        for (int mt = 0; mt < 4; ++mt) {
            int row = mt * 16 + ll;
            bf16x8 afrag = *(const bf16x8*)(lds + XHAT_OFF + row * 256 +
                                            ((kt * 64 + lg * 16) ^ ((row & 7) << 4)));
            acc[mt] = __builtin_amdgcn_mfma_f32_16x16x32_bf16(afrag, bfrag, acc[mt], 0, 0, 0);
        }
    }
    __syncthreads();   // xhat free -> h1 alias

    // ---- epilogue 1: z = rstd*(acc - mu*s1) + c1, ReLU -> h1 bf16 ----
    const int n = w * 16 + ll;
    const float s1v = s1g[t * HH + n];
    const float c1v = c1g[t * HH + n];
    #pragma unroll
    for (int mt = 0; mt < 4; ++mt) {
        #pragma unroll
        for (int j = 0; j < 4; ++j) {
            int el = mt * 16 + lg * 4 + j;
            float2 st = stats[el];
            float z = st.y * (acc[mt][j] - st.x * s1v) + c1v;
            z = fmaxf(z, 0.0f);
            *(unsigned short*)(lds + H1_OFF + el * 144 + n * 2) =
                (unsigned short)((__float_as_uint(z) + 0x8000u) >> 16);
        }
    }
    __syncthreads();

    // ---- GEMM2 ----
    f32x4 acc2 = (f32x4){0.f, 0.f, 0.f, 0.f};
    #pragma unroll
    for (int kt = 0; kt < 2; ++kt) {
        bf16x8 bfrag = ((const bf16x8*)W2p)[(t * 2 + kt) * 64 + lane];
        bf16x8 afrag = *(const bf16x8*)(lds + H1_OFF + (w * 16 + ll) * 144 + kt * 64 + lg * 16);
        acc2 = __builtin_amdgcn_mfma_f32_16x16x32_bf16(afrag, bfrag, acc2, 0, 0, 0);
    }

    // ---- softmax rows of 4, out = I - attn ----
    const float b2v = b2[t * DD + ll];
    const float diag = ((ll >> 2) == (ll & 3)) ? 1.0f : 0.0f;
    #pragma unroll
    for (int j = 0; j < 4; ++j) {
        float o = acc2[j] + b2v;
        float m = fmaxf(o, __shfl_xor(o, 1));
        m = fmaxf(m, __shfl_xor(m, 2));
        float p = __expf(o - m);
        float su = p + __shfl_xor(p, 1);
        su += __shfl_xor(su, 2);
        float res = diag - p / su;
        int el = w * 16 + lg * 4 + j;
        if (TMP) dst[(size_t)(base + el) * DD + ll] = res;
        else     dst[(size_t)sid[el] * DD + ll] = res;
    }
}

// ---------------- P5 (fallback): f32 gather, in-kernel stats ----------------
__global__ __launch_bounds__(256, 8) void sheaf_main_fb(
    const float* __restrict__ x, const float* __restrict__ b2,
    const unsigned short* __restrict__ W1p, const unsigned short* __restrict__ W2p,
    const float* __restrict__ s1g, const float* __restrict__ c1g,
    const int* __restrict__ po, const int* __restrict__ counts,
    const int* __restrict__ sorted, const int* __restrict__ srow,
    const int* __restrict__ scol,
    float* __restrict__ out)
{
    __shared__ __align__(16) unsigned char lds[LDS_BYTES];
    const int base = blockIdx.x * 64;
    if (base >= po[NT]) return;
    int t = 0;
    while (base >= po[t + 1]) ++t;

    const int tid = threadIdx.x;
    const int w = tid >> 6, lane = tid & 63;
    const int lg = lane >> 4, ll = lane & 15;
    int* sid  = (int*)(lds + SID_OFF);
    int* rbuf = (int*)(lds + RB_OFF);
    int* cbuf = (int*)(lds + CB_OFF);

    if (tid < 64) {
        int slot = base + tid;
        int lim = po[t] + counts[t];
        int src = slot < lim ? slot : po[t];
        rbuf[tid] = srow[src]; cbuf[tid] = scol[src]; sid[tid] = sorted[src];
    }
    __syncthreads();

    float s[4] = {0,0,0,0}, sq[4] = {0,0,0,0};
    #pragma unroll
    for (int i = 0; i < 4; ++i) {
        const int el = w * 16 + i * 4 + lg;
        const float4* px = (const float4*)(x + (size_t)rbuf[el] * CC + ll * 8);
        float4 p = px[0], q = px[1];
        s[i] += p.x+p.y+p.z+p.w+q.x+q.y+q.z+q.w;
        sq[i] = fmaf(p.x,p.x,sq[i]); sq[i] = fmaf(p.y,p.y,sq[i]);
        sq[i] = fmaf(p.z,p.z,sq[i]); sq[i] = fmaf(p.w,p.w,sq[i]);
        sq[i] = fmaf(q.x,q.x,sq[i]); sq[i] = fmaf(q.y,q.y,sq[i]);
        sq[i] = fmaf(q.z,q.z,sq[i]); sq[i] = fmaf(q.w,q.w,sq[i]);
        uint4 u;
        u.x = pkbf(p.x,p.y); u.y = pkbf(p.z,p.w); u.z = pkbf(q.x,q.y); u.w = pkbf(q.z,q.w);
        *(uint4*)(lds + XHAT_OFF + el * 256 + ((ll * 16) ^ ((el & 7) << 4))) = u;
    }
    __syncthreads();

    f32x4 acc[4];
    #pragma unroll
    for (int mt = 0; mt < 4; ++mt) acc[mt] = (f32x4){0.f,0.f,0.f,0.f};
    const bf16x8* Bp = (const bf16x8*)W1p + (size_t)((t * 4 + w) * 8) * 64 + lane;
    #pragma unroll
    for (int kt = 0; kt < 4; ++kt) {
        bf16x8 bfrag = Bp[kt * 64];
        #pragma unroll
        for (int mt = 0; mt < 4; ++mt) {
            int row = mt * 16 + ll;
            bf16x8 afrag = *(const bf16x8*)(lds + XHAT_OFF + row * 256 +
                                            ((kt * 64 + lg * 16) ^ ((row & 7) << 4)));
            acc[mt] = __builtin_amdgcn_mfma_f32_16x16x32_bf16(afrag, bfrag, acc[mt], 0, 0, 0);
        }
    }
    __syncthreads();

    #pragma unroll
    for (int i = 0; i < 4; ++i) {
        const int el = w * 16 + i * 4 + lg;
        const float4* px = (const float4*)(x + (size_t)cbuf[el] * CC + ll * 8);
        float4 p = px[0], q = px[1];
        s[i] += p.x+p.y+p.z+p.w+q.x+q.y+q.z+q.w;
        sq[i] = fmaf(p.x,p.x,sq[i]); sq[i] = fmaf(p.y,p.y,sq[i]);
        sq[i] = fmaf(p.z,p.z,sq[i]); sq[i] = fmaf(p.w,p.w,sq[i]);
        sq[i] = fmaf(q.x,q.x,sq[i]); sq[i] = fmaf(q.y,q.y,sq[i]);
        sq[i] = fmaf(q.z,q.z,sq[i]); sq[i] = fmaf(q.w,q.w,sq[i]);
        uint4 u;
        u.x = pkbf(p.x,p.y); u.y = pkbf(p.z,p.w); u.z = pkbf(q.x,q.y); u.w = pkbf(q.z,q.w);
        *(uint4*)(lds + XHAT_OFF + el * 256 + ((ll * 16) ^ ((el & 7) << 4))) = u;
    }
    float2* stats = (float2*)(lds + STATS_OFF);
    #pragma unroll
    for (int i = 0; i < 4; ++i) {
        float s_ = s[i], q_ = sq[i];
        #pragma unroll
        for (int off = 1; off < 16; off <<= 1) {
            s_ += __shfl_xor(s_, off); q_ += __shfl_xor(q_, off);
        }
        if (ll == 0) {
            float mu = s_ * (1.0f / TWO_C);
            float var = q_ * (1.0f / TWO_C) - mu * mu;
            stats[w * 16 + i * 4 + lg] = make_float2(mu, rsqrtf(var + 1e-5f));
        }
    }
    __syncthreads();

    #pragma unroll
    for (int kt = 0; kt < 4; ++kt) {
        bf16x8 bfrag = Bp[(4 + kt) * 64];
        #pragma unroll
        for (int mt = 0; mt < 4; ++mt) {
            int row = mt * 16 + ll;
            bf16x8 afrag = *(const bf16x8*)(lds + XHAT_OFF + row * 256 +
                                            ((kt * 64 + lg * 16) ^ ((row & 7) << 4)));
            acc[mt] = __builtin_amdgcn_mfma_f32_16x16x32_bf16(afrag, bfrag, acc[mt], 0, 0, 0);
        }
    }
    __syncthreads();

    const int n = w * 16 + ll;
    const float s1v = s1g[t * HH + n];
    const float c1v = c1g[t * HH + n];
    #pragma unroll
    for (int mt = 0; mt < 4; ++mt) {
        #pragma unroll
        for (int j = 0; j < 4; ++j) {
            int el = mt * 16 + lg * 4 + j;
            float2 st = stats[el];
            float z = st.y * (acc[mt][j] - st.x * s1v) + c1v;
            z = fmaxf(z, 0.0f);
            *(unsigned short*)(lds + H1_OFF + el * 144 + n * 2) =
                (unsigned short)((__float_as_uint(z) + 0x8000u) >> 16);
        }
    }
    __syncthreads();

    f32x4 acc2 = (f32x4){0.f,0.f,0.f,0.f};
    #pragma unroll
    for (int kt = 0; kt < 2; ++kt) {
        bf16x8 bfrag = ((const bf16x8*)W2p)[(t * 2 + kt) * 64 + lane];
        bf16x8 afrag = *(const bf16x8*)(lds + H1_OFF + (w * 16 + ll) * 144 + kt * 64 + lg * 16);
        acc2 = __builtin_amdgcn_mfma_f32_16x16x32_bf16(afrag, bfrag, acc2, 0, 0, 0);
    }
    const float b2v = b2[t * DD + ll];
    const float diag = ((ll >> 2) == (ll & 3)) ? 1.0f : 0.0f;
    #pragma unroll
    for (int j = 0; j < 4; ++j) {
        float o = acc2[j] + b2v;
        float m = fmaxf(o, __shfl_xor(o, 1));
        m = fmaxf(m, __shfl_xor(m, 2));
        float p = __expf(o - m);
        float su = p + __shfl_xor(p, 1);
        su += __shfl_xor(su, 2);
        int el = w * 16 + lg * 4 + j;
        out[(size_t)sid[el] * DD + ll] = diag - p / su;
    }
}

// ---------------- P6: permute tmp (slot order) -> out (edge order) ----
__global__ __launch_bounds__(256) void permute_kernel(const float4* __restrict__ tmp,
                                                      const int* __restrict__ inv,
                                                      float4* __restrict__ out, int E)
{
    int gt = blockIdx.x * 256 + threadIdx.x;
    if (gt >= E * 4) return;
    int e = gt >> 2, p = gt & 3;
    out[gt] = tmp[(size_t)inv[e] * 4 + p];
}

extern "C" void kernel_launch(void* const* d_in, const int* in_sizes, int n_in,
                              void* d_out, int out_size, void* d_ws, size_t ws_size,
                              hipStream_t stream) {
    const float* x          = (const float*)d_in[0];
    const int*   edge_index = (const int*)  d_in[1];
    const int*   edge_types = (const int*)  d_in[2];
    const float* gamma      = (const float*)d_in[3];
    const float* beta       = (const float*)d_in[4];
    const float* W1         = (const float*)d_in[5];
    const float* b1         = (const float*)d_in[6];
    const float* W2         = (const float*)d_in[7];
    const float* b2         = (const float*)d_in[8];
    float* out = (float*)d_out;

    const int E = in_sizes[2];
    const int xtotal = in_sizes[0];
    const int Nn = xtotal / CC;
    const int cap = ((E + 63) & ~63) + 512;
    const int hq = (E + 3) / 4;

    // pack grids (full vs fallback)
    const int grid_full = (17920 + Nn * 16 + hq + 255) / 256;
    const int grid_fb   = (17920 + hq + 255) / 256;

    // ---- workspace: hdr | partial | sorted | srow | scol | packW | SQ | xb | [inv | tmp]
    int* ws_i   = (int*)d_ws;
    int* counts = ws_i;          // [0..7]
    int* cursor = ws_i + 16;     // [16..23]
    int* po     = ws_i + 24;     // [24..32]

    size_t part_off = 256;
    int* partial = (int*)((char*)d_ws + part_off);
    size_t sorted_off = (part_off + (size_t)grid_full * NT * 4 + 255) & ~(size_t)255;
    int* sorted = (int*)((char*)d_ws + sorted_off);
    int* srow   = sorted + cap;
    int* scol   = srow + cap;

    const size_t pack_bytes = (size_t)NT * 4 * 8 * 64 * 8 * 2
                            + (size_t)NT * 2 * 64 * 8 * 2
                            + (size_t)NT * HH * 4 * 2;
    size_t pk_off = (sorted_off + (size_t)3 * cap * 4 + 255) & ~(size_t)255;
    unsigned short* W1p = (unsigned short*)((char*)d_ws + pk_off);
    unsigned short* W2p = W1p + (size_t)NT * 4 * 8 * 64 * 8;
    float* s1g = (float*)(W2p + (size_t)NT * 2 * 64 * 8);
    float* c1g = s1g + NT * HH;

    size_t sq_off = (pk_off + pack_bytes + 255) & ~(size_t)255;
    float2* SQ = (float2*)((char*)d_ws + sq_off);
    size_t xb_off = (sq_off + (size_t)Nn * 8 + 255) & ~(size_t)255;
    unsigned short* xb = (unsigned short*)((char*)d_ws + xb_off);
    const size_t xb_end = xb_off + (size_t)xtotal * 2;

    const int use_full = (ws_size >= xb_end) ? 1 : 0;

    size_t inv_off = (xb_end + 255) & ~(size_t)255;
    size_t tmp_off = (inv_off + (size_t)cap * 4 + 255) & ~(size_t)255;
    const int use_tmp = (use_full && ws_size >= tmp_off + (size_t)cap * DD * 4) ? 1 : 0;
    int* inv = (int*)((char*)d_ws + inv_off);
    float* tmp = (float*)((char*)d_ws + tmp_off);

    const int histBase = 17920 + (use_full ? Nn * 16 : 0);
    const int grid_pack = use_full ? grid_full : grid_fb;

    hipLaunchKernelGGL(pack_kernel, dim3(grid_pack), dim3(256), 0, stream,
                       W1, W2, gamma, beta, b1, x, W1p, W2p, s1g, c1g,
                       xb, SQ, use_full ? Nn : 0,
                       edge_types, partial, histBase, E);

    hipLaunchKernelGGL(scan_kernel, dim3(1), dim3(256), 0, stream,
                       partial, grid_pack, counts, po, cursor);

    hipLaunchKernelGGL(scatter_kernel, dim3((hq + 255) / 256), dim3(256), 0, stream,
                       edge_types, edge_index, cursor, sorted, srow, scol, inv, E, use_tmp);

    const int gmain = cap / 64;
    if (use_full) {
        if (use_tmp) {
            hipLaunchKernelGGL((sheaf_main_full<1>), dim3(gmain), dim3(256), 0, stream,
                               xb, b2, W1p, W2p, s1g, c1g, SQ, po, counts,
                               sorted, srow, scol, tmp);
            hipLaunchKernelGGL(permute_kernel, dim3((E * 4 + 255) / 256), dim3(256), 0, stream,
                               (const float4*)tmp, inv, (float4*)out, E);
        } else {
            hipLaunchKernelGGL((sheaf_main_full<0>), dim3(gmain), dim3(256), 0, stream,
                               xb, b2, W1p, W2p, s1g, c1g, SQ, po, counts,
                               sorted, srow, scol, out);
        }
    } else {
        hipLaunchKernelGGL(sheaf_main_fb, dim3(gmain), dim3(256), 0, stream,
                           x, b2, W1p, W2p, s1g, c1g, po, counts,
                           sorted, srow, scol, out);
    }
}

// Round 9
// 84.202 us; speedup vs baseline: 1.0930x; 1.0930x over previous
//
#include <hip/hip_runtime.h>
#include <math.h>

#define CC 128
#define TWO_C 256
#define NT 8
#define HH 64
#define DD 16

typedef short bf16x8 __attribute__((ext_vector_type(8)));
typedef float f32x4 __attribute__((ext_vector_type(4)));

static __device__ __forceinline__ unsigned short f2bf_rne(float f) {
    union { float f; unsigned int u; } v; v.f = f;
    unsigned int r = (v.u + 0x7fffu + ((v.u >> 16) & 1u)) >> 16;
    return (unsigned short)r;
}
static __device__ __forceinline__ unsigned int pkbf(float a, float b) {
    unsigned int ua = __float_as_uint(a) + 0x8000u;
    unsigned int ub = __float_as_uint(b) + 0x8000u;
    return (ua >> 16) | (ub & 0xffff0000u);
}
// async global->LDS, 16B per lane; LDS dest wave-uniform base + lane*16
static __device__ __forceinline__ void glds16(const void* g, void* l) {
    __builtin_amdgcn_global_load_lds(
        (const __attribute__((address_space(1))) void*)g,
        (__attribute__((address_space(3))) void*)l, 16, 0, 0);
}

// ---------------- P0: weight pack + s1/c1 + x->bf16 + per-node S,Q ----
__global__ __launch_bounds__(256) void pack_kernel(
    const float* __restrict__ W1, const float* __restrict__ W2,
    const float* __restrict__ gamma, const float* __restrict__ beta,
    const float* __restrict__ b1, const float* __restrict__ x,
    unsigned short* __restrict__ W1p, unsigned short* __restrict__ W2p,
    float* __restrict__ s1g, float* __restrict__ c1g,
    unsigned short* __restrict__ xb, float2* __restrict__ SQ, int Nnodes)
{
    const int tid = blockIdx.x * 256 + threadIdx.x;

    if (tid < 16384) {
        int l = tid & 63, kt = (tid >> 6) & 7, nt = (tid >> 9) & 3, t = tid >> 11;
        int n = nt * 16 + (l & 15);
        int k0 = kt * 32 + (l >> 4) * 8;
        #pragma unroll
        for (int j = 0; j < 8; ++j) {
            int k = k0 + j;
            float v = gamma[t * TWO_C + k] * W1[(size_t)t * TWO_C * HH + (size_t)k * HH + n];
            W1p[tid * 8 + j] = f2bf_rne(v);
        }
    } else if (tid < 17408) {
        int s = tid - 16384;
        int l = s & 63, kt = (s >> 6) & 1, t = s >> 7;
        int n = l & 15;
        int k0 = kt * 32 + (l >> 4) * 8;
        #pragma unroll
        for (int j = 0; j < 8; ++j)
            W2p[s * 8 + j] = f2bf_rne(W2[(size_t)t * HH * DD + (size_t)(k0 + j) * DD + n]);
    } else if (tid < 17920) {
        int s = tid - 17408;
        int t = s >> 6, n = s & 63;
        float sa = 0.f, ca = 0.f;
        for (int k = 0; k < TWO_C; ++k) {
            float wv = W1[(size_t)t * TWO_C * HH + (size_t)k * HH + n];
            sa = fmaf(gamma[t * TWO_C + k], wv, sa);
            ca = fmaf(beta[t * TWO_C + k], wv, ca);
        }
        s1g[s] = sa;
        c1g[s] = ca + b1[s];
    } else {
        // 16 lanes per node: xb conversion + per-node S,Q (f32-exact moments)
        int idx = tid - 17920;
        int v = idx >> 4;
        if (v < Nnodes) {
            int ll = idx & 15;
            int base = idx * 8;          // == v*128 + ll*8
            float4 p = *(const float4*)(x + base);
            float4 q = *(const float4*)(x + base + 4);
            uint4 u;
            u.x = pkbf(p.x, p.y); u.y = pkbf(p.z, p.w);
            u.z = pkbf(q.x, q.y); u.w = pkbf(q.z, q.w);
            *(uint4*)(xb + base) = u;
            float s  = p.x + p.y + p.z + p.w + q.x + q.y + q.z + q.w;
            float sq = p.x*p.x + p.y*p.y + p.z*p.z + p.w*p.w
                     + q.x*q.x + q.y*q.y + q.z*q.z + q.w*q.w;
            #pragma unroll
            for (int off = 1; off < 16; off <<= 1) {
                s  += __shfl_xor(s, off);
                sq += __shfl_xor(sq, off);
            }
            if (ll == 0) SQ[v] = make_float2(s, sq);
        }
    }
}

// ---------------- P1: histogram ----------------
__global__ __launch_bounds__(256) void hist_kernel(const int* __restrict__ et,
                                                   int* __restrict__ counts, int E)
{
    __shared__ int lh[NT];
    if (threadIdx.x < NT) lh[threadIdx.x] = 0;
    __syncthreads();
    int i0 = (blockIdx.x * 256 + threadIdx.x) * 4;
    if (i0 + 3 < E) {
        int4 tv = *(const int4*)(et + i0);
        atomicAdd(&lh[tv.x], 1); atomicAdd(&lh[tv.y], 1);
        atomicAdd(&lh[tv.z], 1); atomicAdd(&lh[tv.w], 1);
    } else {
        #pragma unroll
        for (int j = 0; j < 4; ++j)
            if (i0 + j < E) atomicAdd(&lh[et[i0 + j]], 1);
    }
    __syncthreads();
    if (threadIdx.x < NT && lh[threadIdx.x]) atomicAdd(&counts[threadIdx.x], lh[threadIdx.x]);
}

// ---------------- P2: padded exclusive scan ----------------
__global__ void scan_kernel(const int* __restrict__ counts, int* __restrict__ po,
                            int* __restrict__ cursor)
{
    if (threadIdx.x == 0 && blockIdx.x == 0) {
        int acc = 0;
        for (int t = 0; t < NT; ++t) {
            po[t] = acc;
            cursor[t] = acc;
            acc += ((counts[t] + 63) >> 6) << 6;
        }
        po[NT] = acc;
    }
}

// ---------------- P3: scatter ----------------
__global__ __launch_bounds__(256) void scatter_kernel(const int* __restrict__ et,
                                                      const int* __restrict__ ei,
                                                      int* __restrict__ cursor,
                                                      int* __restrict__ sorted,
                                                      int* __restrict__ srow,
                                                      int* __restrict__ scol,
                                                      int* __restrict__ inv,
                                                      int E, int write_inv)
{
    __shared__ int lh[NT], lbase[NT];
    if (threadIdx.x < NT) lh[threadIdx.x] = 0;
    __syncthreads();
    int i0 = (blockIdx.x * 256 + threadIdx.x) * 4;
    int tl[4], rk[4];
    #pragma unroll
    for (int j = 0; j < 4; ++j) {
        int i = i0 + j;
        if (i < E) { tl[j] = et[i]; rk[j] = atomicAdd(&lh[tl[j]], 1); }
    }
    __syncthreads();
    if (threadIdx.x < NT)
        lbase[threadIdx.x] = lh[threadIdx.x] ? atomicAdd(&cursor[threadIdx.x], lh[threadIdx.x]) : 0;
    __syncthreads();
    #pragma unroll
    for (int j = 0; j < 4; ++j) {
        int i = i0 + j;
        if (i < E) {
            int slot = lbase[tl[j]] + rk[j];
            sorted[slot] = i;
            srow[slot] = ei[i];
            scol[slot] = ei[E + i];
            if (write_inv) inv[i] = slot;
        }
    }
}

// LDS map: [0,16384) xhat half-tile bf16 [64][256B] XOR-swz; h1 [64][144B] aliased
//          [16384,16896) stats float2[64]; [16896,17152) sid; [17152,17408) rbuf; [17408,17664) cbuf
#define XHAT_OFF 0
#define H1_OFF   0
#define STATS_OFF 16384
#define SID_OFF   16896
#define RB_OFF    17152
#define CB_OFF    17408
#define LDS_BYTES 17664

// ---------------- P5 (full): glds staging, precomputed moments ----------------
template <int TMP>
__global__ __launch_bounds__(256, 8) void sheaf_main_full(
    const unsigned short* __restrict__ xb, const float* __restrict__ b2,
    const unsigned short* __restrict__ W1p, const unsigned short* __restrict__ W2p,
    const float* __restrict__ s1g, const float* __restrict__ c1g,
    const float2* __restrict__ SQ,
    const int* __restrict__ po, const int* __restrict__ counts,
    const int* __restrict__ sorted, const int* __restrict__ srow,
    const int* __restrict__ scol,
    float* __restrict__ dst)
{
    __shared__ __align__(16) unsigned char lds[LDS_BYTES];
    const int base = blockIdx.x * 64;
    if (base >= po[NT]) return;
    int t = 0;
    while (base >= po[t + 1]) ++t;
    const int lim = po[t] + counts[t];
    if (base >= lim) return;          // pure-padding tile: nothing consumes it

    const int tid = threadIdx.x;
    const int w = tid >> 6, lane = tid & 63;
    const int lg = lane >> 4, ll = lane & 15;

    int* sid  = (int*)(lds + SID_OFF);
    int* rbuf = (int*)(lds + RB_OFF);
    int* cbuf = (int*)(lds + CB_OFF);
    float2* stats = (float2*)(lds + STATS_OFF);

    if (tid < 64) {
        int slot = base + tid;
        int src = slot < lim ? slot : po[t];      // padding: replicate bucket head
        rbuf[tid] = srow[src];
        cbuf[tid] = scol[src];
        if (!TMP) sid[tid] = sorted[src];
    }
    __syncthreads();

    // ---- stage half A (x[row]) via global_load_lds, source pre-swizzled ----
    #pragma unroll
    for (int i = 0; i < 4; ++i) {
        const int el = w * 16 + i * 4 + lg;
        const unsigned short* src = xb + (size_t)rbuf[el] * CC + ((ll ^ (el & 7)) * 8);
        glds16(src, lds + XHAT_OFF + (w * 16 + i * 4) * 256);
    }
    // ---- LN moments from per-node S,Q (overlaps glds latency) ----
    if (tid < 64) {
        float2 a = SQ[rbuf[tid]];
        float2 b = SQ[cbuf[tid]];
        float mu  = (a.x + b.x) * (1.0f / TWO_C);
        float var = (a.y + b.y) * (1.0f / TWO_C) - mu * mu;
        stats[tid] = make_float2(mu, rsqrtf(var + 1e-5f));
    }
    __syncthreads();   // drains vmcnt: A staged, stats ready

    // ---- GEMM1 half A (k 0..127) ----
    f32x4 acc[4];
    #pragma unroll
    for (int mt = 0; mt < 4; ++mt) acc[mt] = (f32x4){0.f, 0.f, 0.f, 0.f};
    const bf16x8* Bp = (const bf16x8*)W1p + (size_t)((t * 4 + w) * 8) * 64 + lane;
    #pragma unroll
    for (int kt = 0; kt < 4; ++kt) {
        bf16x8 bfrag = Bp[kt * 64];
        #pragma unroll
        for (int mt = 0; mt < 4; ++mt) {
            int row = mt * 16 + ll;
            bf16x8 afrag = *(const bf16x8*)(lds + XHAT_OFF + row * 256 +
                                            ((kt * 64 + lg * 16) ^ ((row & 7) << 4)));
            acc[mt] = __builtin_amdgcn_mfma_f32_16x16x32_bf16(afrag, bfrag, acc[mt], 0, 0, 0);
        }
    }
    __syncthreads();   // all waves done reading A

    // ---- stage half B (x[col]) ----
    #pragma unroll
    for (int i = 0; i < 4; ++i) {
        const int el = w * 16 + i * 4 + lg;
        const unsigned short* src = xb + (size_t)cbuf[el] * CC + ((ll ^ (el & 7)) * 8);
        glds16(src, lds + XHAT_OFF + (w * 16 + i * 4) * 256);
    }
    __syncthreads();   // B staged

    // ---- GEMM1 half B (k 128..255) ----
    #pragma unroll
    for (int kt = 0; kt < 4; ++kt) {
        bf16x8 bfrag = Bp[(4 + kt) * 64];
        #pragma unroll
        for (int mt = 0; mt < 4; ++mt) {
            int row = mt * 16 + ll;
            bf16x8 afrag = *(const bf16x8*)(lds + XHAT_OFF + row * 256 +
                                            ((kt * 64 + lg * 16) ^ ((row & 7) << 4)));
            acc[mt] = __builtin_amdgcn_mfma_f32_16x16x32_bf16(afrag, bfrag, acc[mt], 0, 0, 0);
        }
    }
    __syncthreads();   // xhat free -> h1 alias

    // ---- epilogue 1: z = rstd*(acc - mu*s1) + c1, ReLU -> h1 bf16 ----
    const int n = w * 16 + ll;
    const float s1v = s1g[t * HH + n];
    const float c1v = c1g[t * HH + n];
    #pragma unroll
    for (int mt = 0; mt < 4; ++mt) {
        #pragma unroll
        for (int j = 0; j < 4; ++j) {
            int el = mt * 16 + lg * 4 + j;
            float2 st = stats[el];
            float z = st.y * (acc[mt][j] - st.x * s1v) + c1v;
            z = fmaxf(z, 0.0f);
            *(unsigned short*)(lds + H1_OFF + el * 144 + n * 2) =
                (unsigned short)((__float_as_uint(z) + 0x8000u) >> 16);
        }
    }
    __syncthreads();

    // ---- GEMM2 ----
    f32x4 acc2 = (f32x4){0.f, 0.f, 0.f, 0.f};
    #pragma unroll
    for (int kt = 0; kt < 2; ++kt) {
        bf16x8 bfrag = ((const bf16x8*)W2p)[(t * 2 + kt) * 64 + lane];
        bf16x8 afrag = *(const bf16x8*)(lds + H1_OFF + (w * 16 + ll) * 144 + kt * 64 + lg * 16);
        acc2 = __builtin_amdgcn_mfma_f32_16x16x32_bf16(afrag, bfrag, acc2, 0, 0, 0);
    }

    // ---- softmax rows of 4, out = I - attn ----
    const float b2v = b2[t * DD + ll];
    const float diag = ((ll >> 2) == (ll & 3)) ? 1.0f : 0.0f;
    #pragma unroll
    for (int j = 0; j < 4; ++j) {
        float o = acc2[j] + b2v;
        float m = fmaxf(o, __shfl_xor(o, 1));
        m = fmaxf(m, __shfl_xor(m, 2));
        float p = __expf(o - m);
        float su = p + __shfl_xor(p, 1);
        su += __shfl_xor(su, 2);
        float res = diag - p / su;
        int el = w * 16 + lg * 4 + j;
        if (TMP) dst[(size_t)(base + el) * DD + ll] = res;
        else     dst[(size_t)sid[el] * DD + ll] = res;
    }
}

// ---------------- P5 (fallback): f32 gather, in-kernel stats ----------------
__global__ __launch_bounds__(256, 8) void sheaf_main_fb(
    const float* __restrict__ x, const float* __restrict__ b2,
    const unsigned short* __restrict__ W1p, const unsigned short* __restrict__ W2p,
    const float* __restrict__ s1g, const float* __restrict__ c1g,
    const int* __restrict__ po, const int* __restrict__ counts,
    const int* __restrict__ sorted, const int* __restrict__ srow,
    const int* __restrict__ scol,
    float* __restrict__ out)
{
    __shared__ __align__(16) unsigned char lds[LDS_BYTES];
    const int base = blockIdx.x * 64;
    if (base >= po[NT]) return;
    int t = 0;
    while (base >= po[t + 1]) ++t;
    const int lim = po[t] + counts[t];
    if (base >= lim) return;

    const int tid = threadIdx.x;
    const int w = tid >> 6, lane = tid & 63;
    const int lg = lane >> 4, ll = lane & 15;
    int* sid  = (int*)(lds + SID_OFF);
    int* rbuf = (int*)(lds + RB_OFF);
    int* cbuf = (int*)(lds + CB_OFF);

    if (tid < 64) {
        int slot = base + tid;
        int src = slot < lim ? slot : po[t];
        rbuf[tid] = srow[src]; cbuf[tid] = scol[src]; sid[tid] = sorted[src];
    }
    __syncthreads();

    float s[4] = {0,0,0,0}, sq[4] = {0,0,0,0};
    #pragma unroll
    for (int i = 0; i < 4; ++i) {
        const int el = w * 16 + i * 4 + lg;
        const float4* px = (const float4*)(x + (size_t)rbuf[el] * CC + ll * 8);
        float4 p = px[0], q = px[1];
        s[i] += p.x+p.y+p.z+p.w+q.x+q.y+q.z+q.w;
        sq[i] = fmaf(p.x,p.x,sq[i]); sq[i] = fmaf(p.y,p.y,sq[i]);
        sq[i] = fmaf(p.z,p.z,sq[i]); sq[i] = fmaf(p.w,p.w,sq[i]);
        sq[i] = fmaf(q.x,q.x,sq[i]); sq[i] = fmaf(q.y,q.y,sq[i]);
        sq[i] = fmaf(q.z,q.z,sq[i]); sq[i] = fmaf(q.w,q.w,sq[i]);
        uint4 u;
        u.x = pkbf(p.x,p.y); u.y = pkbf(p.z,p.w); u.z = pkbf(q.x,q.y); u.w = pkbf(q.z,q.w);
        *(uint4*)(lds + XHAT_OFF + el * 256 + ((ll * 16) ^ ((el & 7) << 4))) = u;
    }
    __syncthreads();

    f32x4 acc[4];
    #pragma unroll
    for (int mt = 0; mt < 4; ++mt) acc[mt] = (f32x4){0.f,0.f,0.f,0.f};
    const bf16x8* Bp = (const bf16x8*)W1p + (size_t)((t * 4 + w) * 8) * 64 + lane;
    #pragma unroll
    for (int kt = 0; kt < 4; ++kt) {
        bf16x8 bfrag = Bp[kt * 64];
        #pragma unroll
        for (int mt = 0; mt < 4; ++mt) {
            int row = mt * 16 + ll;
            bf16x8 afrag = *(const bf16x8*)(lds + XHAT_OFF + row * 256 +
                                            ((kt * 64 + lg * 16) ^ ((row & 7) << 4)));
            acc[mt] = __builtin_amdgcn_mfma_f32_16x16x32_bf16(afrag, bfrag, acc[mt], 0, 0, 0);
        }
    }
    __syncthreads();

    #pragma unroll
    for (int i = 0; i < 4; ++i) {
        const int el = w * 16 + i * 4 + lg;
        const float4* px = (const float4*)(x + (size_t)cbuf[el] * CC + ll * 8);
        float4 p = px[0], q = px[1];
        s[i] += p.x+p.y+p.z+p.w+q.x+q.y+q.z+q.w;
        sq[i] = fmaf(p.x,p.x,sq[i]); sq[i] = fmaf(p.y,p.y,sq[i]);
        sq[i] = fmaf(p.z,p.z,sq[i]); sq[i] = fmaf(p.w,p.w,sq[i]);
        sq[i] = fmaf(q.x,q.x,sq[i]); sq[i] = fmaf(q.y,q.y,sq[i]);
        sq[i] = fmaf(q.z,q.z,sq[i]); sq[i] = fmaf(q.w,q.w,sq[i]);
        uint4 u;
        u.x = pkbf(p.x,p.y); u.y = pkbf(p.z,p.w); u.z = pkbf(q.x,q.y); u.w = pkbf(q.z,q.w);
        *(uint4*)(lds + XHAT_OFF + el * 256 + ((ll * 16) ^ ((el & 7) << 4))) = u;
    }
    float2* stats = (float2*)(lds + STATS_OFF);
    #pragma unroll
    for (int i = 0; i < 4; ++i) {
        float s_ = s[i], q_ = sq[i];
        #pragma unroll
        for (int off = 1; off < 16; off <<= 1) {
            s_ += __shfl_xor(s_, off); q_ += __shfl_xor(q_, off);
        }
        if (ll == 0) {
            float mu = s_ * (1.0f / TWO_C);
            float var = q_ * (1.0f / TWO_C) - mu * mu;
            stats[w * 16 + i * 4 + lg] = make_float2(mu, rsqrtf(var + 1e-5f));
        }
    }
    __syncthreads();

    #pragma unroll
    for (int kt = 0; kt < 4; ++kt) {
        bf16x8 bfrag = Bp[(4 + kt) * 64];
        #pragma unroll
        for (int mt = 0; mt < 4; ++mt) {
            int row = mt * 16 + ll;
            bf16x8 afrag = *(const bf16x8*)(lds + XHAT_OFF + row * 256 +
                                            ((kt * 64 + lg * 16) ^ ((row & 7) << 4)));
            acc[mt] = __builtin_amdgcn_mfma_f32_16x16x32_bf16(afrag, bfrag, acc[mt], 0, 0, 0);
        }
    }
    __syncthreads();

    const int n = w * 16 + ll;
    const float s1v = s1g[t * HH + n];
    const float c1v = c1g[t * HH + n];
    #pragma unroll
    for (int mt = 0; mt < 4; ++mt) {
        #pragma unroll
        for (int j = 0; j < 4; ++j) {
            int el = mt * 16 + lg * 4 + j;
            float2 st = stats[el];
            float z = st.y * (acc[mt][j] - st.x * s1v) + c1v;
            z = fmaxf(z, 0.0f);
            *(unsigned short*)(lds + H1_OFF + el * 144 + n * 2) =
                (unsigned short)((__float_as_uint(z) + 0x8000u) >> 16);
        }
    }
    __syncthreads();

    f32x4 acc2 = (f32x4){0.f,0.f,0.f,0.f};
    #pragma unroll
    for (int kt = 0; kt < 2; ++kt) {
        bf16x8 bfrag = ((const bf16x8*)W2p)[(t * 2 + kt) * 64 + lane];
        bf16x8 afrag = *(const bf16x8*)(lds + H1_OFF + (w * 16 + ll) * 144 + kt * 64 + lg * 16);
        acc2 = __builtin_amdgcn_mfma_f32_16x16x32_bf16(afrag, bfrag, acc2, 0, 0, 0);
    }
    const float b2v = b2[t * DD + ll];
    const float diag = ((ll >> 2) == (ll & 3)) ? 1.0f : 0.0f;
    #pragma unroll
    for (int j = 0; j < 4; ++j) {
        float o = acc2[j] + b2v;
        float m = fmaxf(o, __shfl_xor(o, 1));
        m = fmaxf(m, __shfl_xor(m, 2));
        float p = __expf(o - m);
        float su = p + __shfl_xor(p, 1);
        su += __shfl_xor(su, 2);
        int el = w * 16 + lg * 4 + j;
        out[(size_t)sid[el] * DD + ll] = diag - p / su;
    }
}

// ---------------- P6: permute, one edge per thread (64B copy) ----------------
__global__ __launch_bounds__(256) void permute_kernel(const float4* __restrict__ tmp,
                                                      const int* __restrict__ inv,
                                                      float4* __restrict__ out, int E)
{
    int e = blockIdx.x * 256 + threadIdx.x;
    if (e >= E) return;
    int slot = inv[e];
    const float4* s = tmp + (size_t)slot * 4;
    float4 a = s[0], b = s[1], c = s[2], d = s[3];
    float4* o = out + (size_t)e * 4;
    o[0] = a; o[1] = b; o[2] = c; o[3] = d;
}

extern "C" void kernel_launch(void* const* d_in, const int* in_sizes, int n_in,
                              void* d_out, int out_size, void* d_ws, size_t ws_size,
                              hipStream_t stream) {
    const float* x          = (const float*)d_in[0];
    const int*   edge_index = (const int*)  d_in[1];
    const int*   edge_types = (const int*)  d_in[2];
    const float* gamma      = (const float*)d_in[3];
    const float* beta       = (const float*)d_in[4];
    const float* W1         = (const float*)d_in[5];
    const float* b1         = (const float*)d_in[6];
    const float* W2         = (const float*)d_in[7];
    const float* b2         = (const float*)d_in[8];
    float* out = (float*)d_out;

    const int E = in_sizes[2];
    const int xtotal = in_sizes[0];
    const int Nn = xtotal / CC;
    const int cap = ((E + 63) & ~63) + 512;

    // ---- workspace: hdr | sorted | srow | scol | packW | SQ | xb | [inv | tmp] ----
    int* ws_i   = (int*)d_ws;
    int* counts = ws_i;          // [0..7]
    int* cursor = ws_i + 16;     // [16..23]
    int* po     = ws_i + 24;     // [24..32]
    int* sorted = ws_i + 40;
    int* srow   = sorted + cap;
    int* scol   = srow + cap;

    const size_t pack_bytes = (size_t)NT * 4 * 8 * 64 * 8 * 2
                            + (size_t)NT * 2 * 64 * 8 * 2
                            + (size_t)NT * HH * 4 * 2;
    size_t pk_off = (((size_t)(40 + 3 * (size_t)cap)) * 4 + 255) & ~(size_t)255;
    unsigned short* W1p = (unsigned short*)((char*)d_ws + pk_off);
    unsigned short* W2p = W1p + (size_t)NT * 4 * 8 * 64 * 8;
    float* s1g = (float*)(W2p + (size_t)NT * 2 * 64 * 8);
    float* c1g = s1g + NT * HH;

    size_t sq_off = (pk_off + pack_bytes + 255) & ~(size_t)255;
    float2* SQ = (float2*)((char*)d_ws + sq_off);
    size_t xb_off = (sq_off + (size_t)Nn * 8 + 255) & ~(size_t)255;
    unsigned short* xb = (unsigned short*)((char*)d_ws + xb_off);
    const size_t xb_end = xb_off + (size_t)xtotal * 2;

    const int use_full = (ws_size >= xb_end) ? 1 : 0;

    size_t inv_off = (xb_end + 255) & ~(size_t)255;
    size_t tmp_off = (inv_off + (size_t)cap * 4 + 255) & ~(size_t)255;
    const int use_tmp = (use_full && ws_size >= tmp_off + (size_t)cap * DD * 4) ? 1 : 0;
    int* inv = (int*)((char*)d_ws + inv_off);
    float* tmp = (float*)((char*)d_ws + tmp_off);

    hipMemsetAsync(counts, 0, 32, stream);

    const int pt = use_full ? (17920 + Nn * 16) : 17920;
    hipLaunchKernelGGL(pack_kernel, dim3((pt + 255) / 256), dim3(256), 0, stream,
                       W1, W2, gamma, beta, b1, x, W1p, W2p, s1g, c1g,
                       xb, SQ, use_full ? Nn : 0);

    const int hq = (E + 3) / 4;
    hipLaunchKernelGGL(hist_kernel, dim3((hq + 255) / 256), dim3(256), 0, stream,
                       edge_types, counts, E);
    hipLaunchKernelGGL(scan_kernel, dim3(1), dim3(64), 0, stream, counts, po, cursor);
    hipLaunchKernelGGL(scatter_kernel, dim3((hq + 255) / 256), dim3(256), 0, stream,
                       edge_types, edge_index, cursor, sorted, srow, scol, inv, E, use_tmp);

    const int gmain = cap / 64;
    if (use_full) {
        if (use_tmp) {
            hipLaunchKernelGGL((sheaf_main_full<1>), dim3(gmain), dim3(256), 0, stream,
                               xb, b2, W1p, W2p, s1g, c1g, SQ, po, counts,
                               sorted, srow, scol, tmp);
            hipLaunchKernelGGL(permute_kernel, dim3((E + 255) / 256), dim3(256), 0, stream,
                               (const float4*)tmp, inv, (float4*)out, E);
        } else {
            hipLaunchKernelGGL((sheaf_main_full<0>), dim3(gmain), dim3(256), 0, stream,
                               xb, b2, W1p, W2p, s1g, c1g, SQ, po, counts,
                               sorted, srow, scol, out);
        }
    } else {
        hipLaunchKernelGGL(sheaf_main_fb, dim3(gmain), dim3(256), 0, stream,
                           x, b2, W1p, W2p, s1g, c1g, po, counts,
                           sorted, srow, scol, out);
    }
}

// Round 10
// 70.545 us; speedup vs baseline: 1.3045x; 1.1936x over previous
//
#include <hip/hip_runtime.h>
#include <math.h>

#define CC 128
#define TWO_C 256
#define NT 8
#define HH 64
#define DD 16

typedef short bf16x8 __attribute__((ext_vector_type(8)));
typedef float f32x4 __attribute__((ext_vector_type(4)));

static __device__ __forceinline__ unsigned short f2bf_rne(float f) {
    union { float f; unsigned int u; } v; v.f = f;
    unsigned int r = (v.u + 0x7fffu + ((v.u >> 16) & 1u)) >> 16;
    return (unsigned short)r;
}
static __device__ __forceinline__ unsigned int pkbf(float a, float b) {
    unsigned int ua = __float_as_uint(a) + 0x8000u;
    unsigned int ub = __float_as_uint(b) + 0x8000u;
    return (ua >> 16) | (ub & 0xffff0000u);
}
static __device__ __forceinline__ void glds16(const void* g, void* l) {
    __builtin_amdgcn_global_load_lds(
        (const __attribute__((address_space(1))) void*)g,
        (__attribute__((address_space(3))) void*)l, 16, 0, 0);
}

// ---------------- P0: weight pack + s1/c1 (wave-parallel) + x->bf16 + per-node S,Q
// tid segments: [0,16384) W1p | [16384,17408) W2p | [17408,50176) s1/c1 | [50176,..) xb+SQ
__global__ __launch_bounds__(256) void pack_kernel(
    const float* __restrict__ W1, const float* __restrict__ W2,
    const float* __restrict__ gamma, const float* __restrict__ beta,
    const float* __restrict__ b1, const float* __restrict__ x,
    unsigned short* __restrict__ W1p, unsigned short* __restrict__ W2p,
    float* __restrict__ s1g, float* __restrict__ c1g,
    unsigned short* __restrict__ xb, float2* __restrict__ SQ, int Nnodes)
{
    const int tid = blockIdx.x * 256 + threadIdx.x;

    if (tid < 16384) {
        int l = tid & 63, kt = (tid >> 6) & 7, nt = (tid >> 9) & 3, t = tid >> 11;
        int n = nt * 16 + (l & 15);
        int k0 = kt * 32 + (l >> 4) * 8;
        #pragma unroll
        for (int j = 0; j < 8; ++j) {
            int k = k0 + j;
            float v = gamma[t * TWO_C + k] * W1[(size_t)t * TWO_C * HH + (size_t)k * HH + n];
            W1p[tid * 8 + j] = f2bf_rne(v);
        }
    } else if (tid < 17408) {
        int s = tid - 16384;
        int l = s & 63, kt = (s >> 6) & 1, t = s >> 7;
        int n = l & 15;
        int k0 = kt * 32 + (l >> 4) * 8;
        #pragma unroll
        for (int j = 0; j < 8; ++j)
            W2p[s * 8 + j] = f2bf_rne(W2[(size_t)t * HH * DD + (size_t)(k0 + j) * DD + n]);
    } else if (tid < 50176) {
        // one 64-lane wave per (t,n): s1 = sum_k gamma*W1, c1 = sum_k beta*W1 + b1
        int id = tid - 17408;
        int lane = id & 63;
        int pair = id >> 6;            // [0,512)
        int t = pair >> 6, n = pair & 63;
        float sa = 0.f, ca = 0.f;
        #pragma unroll
        for (int i = 0; i < 4; ++i) {
            int k = i * 64 + lane;
            float wv = W1[(size_t)t * TWO_C * HH + (size_t)k * HH + n];
            sa = fmaf(gamma[t * TWO_C + k], wv, sa);
            ca = fmaf(beta[t * TWO_C + k], wv, ca);
        }
        #pragma unroll
        for (int off = 1; off < 64; off <<= 1) {
            sa += __shfl_xor(sa, off);
            ca += __shfl_xor(ca, off);
        }
        if (lane == 0) {
            s1g[pair] = sa;
            c1g[pair] = ca + b1[pair];
        }
    } else {
        // 16 lanes per node: xb conversion + per-node S,Q
        int idx = tid - 50176;
        int v = idx >> 4;
        if (v < Nnodes) {
            int ll = idx & 15;
            int base = idx * 8;        // == v*128 + ll*8
            float4 p = *(const float4*)(x + base);
            float4 q = *(const float4*)(x + base + 4);
            uint4 u;
            u.x = pkbf(p.x, p.y); u.y = pkbf(p.z, p.w);
            u.z = pkbf(q.x, q.y); u.w = pkbf(q.z, q.w);
            *(uint4*)(xb + base) = u;
            float s  = p.x + p.y + p.z + p.w + q.x + q.y + q.z + q.w;
            float sq = p.x*p.x + p.y*p.y + p.z*p.z + p.w*p.w
                     + q.x*q.x + q.y*q.y + q.z*q.z + q.w*q.w;
            #pragma unroll
            for (int off = 1; off < 16; off <<= 1) {
                s  += __shfl_xor(s, off);
                sq += __shfl_xor(sq, off);
            }
            if (ll == 0) SQ[v] = make_float2(s, sq);
        }
    }
}

// ---------------- P1 (direct): one-pass scatter into fixed per-type segments ----
__global__ __launch_bounds__(256) void scatter_direct(const int* __restrict__ et,
                                                      const int* __restrict__ ei,
                                                      int* __restrict__ cursor,
                                                      int* __restrict__ srow,
                                                      int* __restrict__ scol,
                                                      int* __restrict__ inv,
                                                      int E, int capE)
{
    __shared__ int lh[NT], lbase[NT];
    if (threadIdx.x < NT) lh[threadIdx.x] = 0;
    __syncthreads();
    int i0 = (blockIdx.x * 256 + threadIdx.x) * 4;
    int tl[4], rk[4];
    #pragma unroll
    for (int j = 0; j < 4; ++j) {
        int i = i0 + j;
        if (i < E) { tl[j] = et[i]; rk[j] = atomicAdd(&lh[tl[j]], 1); }
    }
    __syncthreads();
    if (threadIdx.x < NT)
        lbase[threadIdx.x] = lh[threadIdx.x] ? atomicAdd(&cursor[threadIdx.x], lh[threadIdx.x]) : 0;
    __syncthreads();
    #pragma unroll
    for (int j = 0; j < 4; ++j) {
        int i = i0 + j;
        if (i < E) {
            int slot = tl[j] * capE + lbase[tl[j]] + rk[j];
            srow[slot] = ei[i];
            scol[slot] = ei[E + i];
            inv[i] = slot;
        }
    }
}

// ---------------- fallback prep: hist / scan / scatter (po-based) ----------------
__global__ __launch_bounds__(256) void hist_kernel(const int* __restrict__ et,
                                                   int* __restrict__ counts, int E)
{
    __shared__ int lh[NT];
    if (threadIdx.x < NT) lh[threadIdx.x] = 0;
    __syncthreads();
    int i0 = (blockIdx.x * 256 + threadIdx.x) * 4;
    #pragma unroll
    for (int j = 0; j < 4; ++j)
        if (i0 + j < E) atomicAdd(&lh[et[i0 + j]], 1);
    __syncthreads();
    if (threadIdx.x < NT && lh[threadIdx.x]) atomicAdd(&counts[threadIdx.x], lh[threadIdx.x]);
}

__global__ void scan_kernel(const int* __restrict__ counts, int* __restrict__ po,
                            int* __restrict__ cursor)
{
    if (threadIdx.x == 0 && blockIdx.x == 0) {
        int acc = 0;
        for (int t = 0; t < NT; ++t) {
            po[t] = acc;
            cursor[t] = acc;
            acc += ((counts[t] + 63) >> 6) << 6;
        }
        po[NT] = acc;
    }
}

__global__ __launch_bounds__(256) void scatter_kernel(const int* __restrict__ et,
                                                      const int* __restrict__ ei,
                                                      int* __restrict__ cursor,
                                                      int* __restrict__ sorted,
                                                      int* __restrict__ srow,
                                                      int* __restrict__ scol,
                                                      int E)
{
    __shared__ int lh[NT], lbase[NT];
    if (threadIdx.x < NT) lh[threadIdx.x] = 0;
    __syncthreads();
    int i0 = (blockIdx.x * 256 + threadIdx.x) * 4;
    int tl[4], rk[4];
    #pragma unroll
    for (int j = 0; j < 4; ++j) {
        int i = i0 + j;
        if (i < E) { tl[j] = et[i]; rk[j] = atomicAdd(&lh[tl[j]], 1); }
    }
    __syncthreads();
    if (threadIdx.x < NT)
        lbase[threadIdx.x] = lh[threadIdx.x] ? atomicAdd(&cursor[threadIdx.x], lh[threadIdx.x]) : 0;
    __syncthreads();
    #pragma unroll
    for (int j = 0; j < 4; ++j) {
        int i = i0 + j;
        if (i < E) {
            int slot = lbase[tl[j]] + rk[j];
            sorted[slot] = i;
            srow[slot] = ei[i];
            scol[slot] = ei[E + i];
        }
    }
}

// LDS map: [0,16384) xhat bf16 [64][256B] XOR-swz; h1 [64][144B] aliased
//          [16384,16896) stats; [16896,17152) sid; [17152,17408) rbuf; [17408,17664) cbuf
#define XHAT_OFF 0
#define H1_OFF   0
#define STATS_OFF 16384
#define SID_OFF   16896
#define RB_OFF    17152
#define CB_OFF    17408
#define LDS_BYTES 17664

// ---------------- main: FIXED=1 arithmetic segments + tmp write; FIXED=0 po-search + scattered out
template <int FIXED>
__global__ __launch_bounds__(256, 8) void sheaf_main_full(
    const unsigned short* __restrict__ xb, const float* __restrict__ b2,
    const unsigned short* __restrict__ W1p, const unsigned short* __restrict__ W2p,
    const float* __restrict__ s1g, const float* __restrict__ c1g,
    const float2* __restrict__ SQ,
    const int* __restrict__ po, const int* __restrict__ counts,
    const int* __restrict__ sorted, const int* __restrict__ srow,
    const int* __restrict__ scol,
    float* __restrict__ dst, int bpt, int capE)
{
    __shared__ __align__(16) unsigned char lds[LDS_BYTES];
    int t, base, lim, segBase;
    if (FIXED) {
        t = blockIdx.x / bpt;
        int inb = (blockIdx.x - t * bpt) * 64;
        lim = counts[t];                 // cursor final value = bucket count
        if (inb >= lim) return;
        segBase = t * capE;
        base = segBase + inb;            // global slot base; lim is within-bucket
        lim += segBase;
    } else {
        base = blockIdx.x * 64;
        if (base >= po[NT]) return;
        t = 0;
        while (base >= po[t + 1]) ++t;
        lim = po[t] + counts[t];
        if (base >= lim) return;
        segBase = po[t];
    }

    const int tid = threadIdx.x;
    const int w = tid >> 6, lane = tid & 63;
    const int lg = lane >> 4, ll = lane & 15;

    int* sid  = (int*)(lds + SID_OFF);
    int* rbuf = (int*)(lds + RB_OFF);
    int* cbuf = (int*)(lds + CB_OFF);
    float2* stats = (float2*)(lds + STATS_OFF);

    if (tid < 64) {
        int slot = base + tid;
        int src = slot < lim ? slot : segBase;    // padding: replicate bucket head
        rbuf[tid] = srow[src];
        cbuf[tid] = scol[src];
        if (!FIXED) sid[tid] = sorted[src];
    }
    __syncthreads();

    // ---- stage half A (x[row]) via global_load_lds, source pre-swizzled ----
    #pragma unroll
    for (int i = 0; i < 4; ++i) {
        const int el = w * 16 + i * 4 + lg;
        const unsigned short* src = xb + (size_t)rbuf[el] * CC + ((ll ^ (el & 7)) * 8);
        glds16(src, lds + XHAT_OFF + (w * 16 + i * 4) * 256);
    }
    if (tid < 64) {
        float2 a = SQ[rbuf[tid]];
        float2 b = SQ[cbuf[tid]];
        float mu  = (a.x + b.x) * (1.0f / TWO_C);
        float var = (a.y + b.y) * (1.0f / TWO_C) - mu * mu;
        stats[tid] = make_float2(mu, rsqrtf(var + 1e-5f));
    }
    __syncthreads();

    // ---- GEMM1 half A ----
    f32x4 acc[4];
    #pragma unroll
    for (int mt = 0; mt < 4; ++mt) acc[mt] = (f32x4){0.f, 0.f, 0.f, 0.f};
    const bf16x8* Bp = (const bf16x8*)W1p + (size_t)((t * 4 + w) * 8) * 64 + lane;
    #pragma unroll
    for (int kt = 0; kt < 4; ++kt) {
        bf16x8 bfrag = Bp[kt * 64];
        #pragma unroll
        for (int mt = 0; mt < 4; ++mt) {
            int row = mt * 16 + ll;
            bf16x8 afrag = *(const bf16x8*)(lds + XHAT_OFF + row * 256 +
                                            ((kt * 64 + lg * 16) ^ ((row & 7) << 4)));
            acc[mt] = __builtin_amdgcn_mfma_f32_16x16x32_bf16(afrag, bfrag, acc[mt], 0, 0, 0);
        }
    }
    __syncthreads();

    // ---- stage half B (x[col]) ----
    #pragma unroll
    for (int i = 0; i < 4; ++i) {
        const int el = w * 16 + i * 4 + lg;
        const unsigned short* src = xb + (size_t)cbuf[el] * CC + ((ll ^ (el & 7)) * 8);
        glds16(src, lds + XHAT_OFF + (w * 16 + i * 4) * 256);
    }
    __syncthreads();

    // ---- GEMM1 half B ----
    #pragma unroll
    for (int kt = 0; kt < 4; ++kt) {
        bf16x8 bfrag = Bp[(4 + kt) * 64];
        #pragma unroll
        for (int mt = 0; mt < 4; ++mt) {
            int row = mt * 16 + ll;
            bf16x8 afrag = *(const bf16x8*)(lds + XHAT_OFF + row * 256 +
                                            ((kt * 64 + lg * 16) ^ ((row & 7) << 4)));
            acc[mt] = __builtin_amdgcn_mfma_f32_16x16x32_bf16(afrag, bfrag, acc[mt], 0, 0, 0);
        }
    }
    __syncthreads();

    // ---- epilogue 1 ----
    const int n = w * 16 + ll;
    const float s1v = s1g[t * HH + n];
    const float c1v = c1g[t * HH + n];
    #pragma unroll
    for (int mt = 0; mt < 4; ++mt) {
        #pragma unroll
        for (int j = 0; j < 4; ++j) {
            int el = mt * 16 + lg * 4 + j;
            float2 st = stats[el];
            float z = st.y * (acc[mt][j] - st.x * s1v) + c1v;
            z = fmaxf(z, 0.0f);
            *(unsigned short*)(lds + H1_OFF + el * 144 + n * 2) =
                (unsigned short)((__float_as_uint(z) + 0x8000u) >> 16);
        }
    }
    __syncthreads();

    // ---- GEMM2 ----
    f32x4 acc2 = (f32x4){0.f, 0.f, 0.f, 0.f};
    #pragma unroll
    for (int kt = 0; kt < 2; ++kt) {
        bf16x8 bfrag = ((const bf16x8*)W2p)[(t * 2 + kt) * 64 + lane];
        bf16x8 afrag = *(const bf16x8*)(lds + H1_OFF + (w * 16 + ll) * 144 + kt * 64 + lg * 16);
        acc2 = __builtin_amdgcn_mfma_f32_16x16x32_bf16(afrag, bfrag, acc2, 0, 0, 0);
    }

    // ---- softmax + write ----
    const float b2v = b2[t * DD + ll];
    const float diag = ((ll >> 2) == (ll & 3)) ? 1.0f : 0.0f;
    #pragma unroll
    for (int j = 0; j < 4; ++j) {
        float o = acc2[j] + b2v;
        float m = fmaxf(o, __shfl_xor(o, 1));
        m = fmaxf(m, __shfl_xor(m, 2));
        float p = __expf(o - m);
        float su = p + __shfl_xor(p, 1);
        su += __shfl_xor(su, 2);
        float res = diag - p / su;
        int el = w * 16 + lg * 4 + j;
        if (FIXED) dst[(size_t)(base + el) * DD + ll] = res;   // tmp, slot order
        else       dst[(size_t)sid[el] * DD + ll] = res;       // out, scattered
    }
}

// ---------------- tiny fallback: f32 gather, in-kernel stats ----------------
__global__ __launch_bounds__(256, 8) void sheaf_main_fb(
    const float* __restrict__ x, const float* __restrict__ b2,
    const unsigned short* __restrict__ W1p, const unsigned short* __restrict__ W2p,
    const float* __restrict__ s1g, const float* __restrict__ c1g,
    const int* __restrict__ po, const int* __restrict__ counts,
    const int* __restrict__ sorted, const int* __restrict__ srow,
    const int* __restrict__ scol,
    float* __restrict__ out)
{
    __shared__ __align__(16) unsigned char lds[LDS_BYTES];
    const int base = blockIdx.x * 64;
    if (base >= po[NT]) return;
    int t = 0;
    while (base >= po[t + 1]) ++t;
    const int lim = po[t] + counts[t];
    if (base >= lim) return;

    const int tid = threadIdx.x;
    const int w = tid >> 6, lane = tid & 63;
    const int lg = lane >> 4, ll = lane & 15;
    int* sid  = (int*)(lds + SID_OFF);
    int* rbuf = (int*)(lds + RB_OFF);
    int* cbuf = (int*)(lds + CB_OFF);

    if (tid < 64) {
        int slot = base + tid;
        int src = slot < lim ? slot : po[t];
        rbuf[tid] = srow[src]; cbuf[tid] = scol[src]; sid[tid] = sorted[src];
    }
    __syncthreads();

    float s[4] = {0,0,0,0}, sq[4] = {0,0,0,0};
    #pragma unroll
    for (int i = 0; i < 4; ++i) {
        const int el = w * 16 + i * 4 + lg;
        const float4* px = (const float4*)(x + (size_t)rbuf[el] * CC + ll * 8);
        float4 p = px[0], q = px[1];
        s[i] += p.x+p.y+p.z+p.w+q.x+q.y+q.z+q.w;
        sq[i] = fmaf(p.x,p.x,sq[i]); sq[i] = fmaf(p.y,p.y,sq[i]);
        sq[i] = fmaf(p.z,p.z,sq[i]); sq[i] = fmaf(p.w,p.w,sq[i]);
        sq[i] = fmaf(q.x,q.x,sq[i]); sq[i] = fmaf(q.y,q.y,sq[i]);
        sq[i] = fmaf(q.z,q.z,sq[i]); sq[i] = fmaf(q.w,q.w,sq[i]);
        uint4 u;
        u.x = pkbf(p.x,p.y); u.y = pkbf(p.z,p.w); u.z = pkbf(q.x,q.y); u.w = pkbf(q.z,q.w);
        *(uint4*)(lds + XHAT_OFF + el * 256 + ((ll * 16) ^ ((el & 7) << 4))) = u;
    }
    __syncthreads();

    f32x4 acc[4];
    #pragma unroll
    for (int mt = 0; mt < 4; ++mt) acc[mt] = (f32x4){0.f,0.f,0.f,0.f};
    const bf16x8* Bp = (const bf16x8*)W1p + (size_t)((t * 4 + w) * 8) * 64 + lane;
    #pragma unroll
    for (int kt = 0; kt < 4; ++kt) {
        bf16x8 bfrag = Bp[kt * 64];
        #pragma unroll
        for (int mt = 0; mt < 4; ++mt) {
            int row = mt * 16 + ll;
            bf16x8 afrag = *(const bf16x8*)(lds + XHAT_OFF + row * 256 +
                                            ((kt * 64 + lg * 16) ^ ((row & 7) << 4)));
            acc[mt] = __builtin_amdgcn_mfma_f32_16x16x32_bf16(afrag, bfrag, acc[mt], 0, 0, 0);
        }
    }
    __syncthreads();

    #pragma unroll
    for (int i = 0; i < 4; ++i) {
        const int el = w * 16 + i * 4 + lg;
        const float4* px = (const float4*)(x + (size_t)cbuf[el] * CC + ll * 8);
        float4 p = px[0], q = px[1];
        s[i] += p.x+p.y+p.z+p.w+q.x+q.y+q.z+q.w;
        sq[i] = fmaf(p.x,p.x,sq[i]); sq[i] = fmaf(p.y,p.y,sq[i]);
        sq[i] = fmaf(p.z,p.z,sq[i]); sq[i] = fmaf(p.w,p.w,sq[i]);
        sq[i] = fmaf(q.x,q.x,sq[i]); sq[i] = fmaf(q.y,q.y,sq[i]);
        sq[i] = fmaf(q.z,q.z,sq[i]); sq[i] = fmaf(q.w,q.w,sq[i]);
        uint4 u;
        u.x = pkbf(p.x,p.y); u.y = pkbf(p.z,p.w); u.z = pkbf(q.x,q.y); u.w = pkbf(q.z,q.w);
        *(uint4*)(lds + XHAT_OFF + el * 256 + ((ll * 16) ^ ((el & 7) << 4))) = u;
    }
    float2* stats = (float2*)(lds + STATS_OFF);
    #pragma unroll
    for (int i = 0; i < 4; ++i) {
        float s_ = s[i], q_ = sq[i];
        #pragma unroll
        for (int off = 1; off < 16; off <<= 1) {
            s_ += __shfl_xor(s_, off); q_ += __shfl_xor(q_, off);
        }
        if (ll == 0) {
            float mu = s_ * (1.0f / TWO_C);
            float var = q_ * (1.0f / TWO_C) - mu * mu;
            stats[w * 16 + i * 4 + lg] = make_float2(mu, rsqrtf(var + 1e-5f));
        }
    }
    __syncthreads();

    #pragma unroll
    for (int kt = 0; kt < 4; ++kt) {
        bf16x8 bfrag = Bp[(4 + kt) * 64];
        #pragma unroll
        for (int mt = 0; mt < 4; ++mt) {
            int row = mt * 16 + ll;
            bf16x8 afrag = *(const bf16x8*)(lds + XHAT_OFF + row * 256 +
                                            ((kt * 64 + lg * 16) ^ ((row & 7) << 4)));
            acc[mt] = __builtin_amdgcn_mfma_f32_16x16x32_bf16(afrag, bfrag, acc[mt], 0, 0, 0);
        }
    }
    __syncthreads();

    const int n = w * 16 + ll;
    const float s1v = s1g[t * HH + n];
    const float c1v = c1g[t * HH + n];
    #pragma unroll
    for (int mt = 0; mt < 4; ++mt) {
        #pragma unroll
        for (int j = 0; j < 4; ++j) {
            int el = mt * 16 + lg * 4 + j;
            float2 st = stats[el];
            float z = st.y * (acc[mt][j] - st.x * s1v) + c1v;
            z = fmaxf(z, 0.0f);
            *(unsigned short*)(lds + H1_OFF + el * 144 + n * 2) =
                (unsigned short)((__float_as_uint(z) + 0x8000u) >> 16);
        }
    }
    __syncthreads();

    f32x4 acc2 = (f32x4){0.f,0.f,0.f,0.f};
    #pragma unroll
    for (int kt = 0; kt < 2; ++kt) {
        bf16x8 bfrag = ((const bf16x8*)W2p)[(t * 2 + kt) * 64 + lane];
        bf16x8 afrag = *(const bf16x8*)(lds + H1_OFF + (w * 16 + ll) * 144 + kt * 64 + lg * 16);
        acc2 = __builtin_amdgcn_mfma_f32_16x16x32_bf16(afrag, bfrag, acc2, 0, 0, 0);
    }
    const float b2v = b2[t * DD + ll];
    const float diag = ((ll >> 2) == (ll & 3)) ? 1.0f : 0.0f;
    #pragma unroll
    for (int j = 0; j < 4; ++j) {
        float o = acc2[j] + b2v;
        float m = fmaxf(o, __shfl_xor(o, 1));
        m = fmaxf(m, __shfl_xor(m, 2));
        float p = __expf(o - m);
        float su = p + __shfl_xor(p, 1);
        su += __shfl_xor(su, 2);
        int el = w * 16 + lg * 4 + j;
        out[(size_t)sid[el] * DD + ll] = diag - p / su;
    }
}

// ---------------- permute: one edge per thread (64B copy) ----------------
__global__ __launch_bounds__(256) void permute_kernel(const float4* __restrict__ tmp,
                                                      const int* __restrict__ inv,
                                                      float4* __restrict__ out, int E)
{
    int e = blockIdx.x * 256 + threadIdx.x;
    if (e >= E) return;
    int slot = inv[e];
    const float4* s = tmp + (size_t)slot * 4;
    float4 a = s[0], b = s[1], c = s[2], d = s[3];
    float4* o = out + (size_t)e * 4;
    o[0] = a; o[1] = b; o[2] = c; o[3] = d;
}

extern "C" void kernel_launch(void* const* d_in, const int* in_sizes, int n_in,
                              void* d_out, int out_size, void* d_ws, size_t ws_size,
                              hipStream_t stream) {
    const float* x          = (const float*)d_in[0];
    const int*   edge_index = (const int*)  d_in[1];
    const int*   edge_types = (const int*)  d_in[2];
    const float* gamma      = (const float*)d_in[3];
    const float* beta       = (const float*)d_in[4];
    const float* W1         = (const float*)d_in[5];
    const float* b1         = (const float*)d_in[6];
    const float* W2         = (const float*)d_in[7];
    const float* b2         = (const float*)d_in[8];
    float* out = (float*)d_out;

    const int E = in_sizes[2];
    const int xtotal = in_sizes[0];
    const int Nn = xtotal / CC;
    const int hq = (E + 3) / 4;

    const size_t pack_bytes = (size_t)NT * 4 * 8 * 64 * 8 * 2
                            + (size_t)NT * 2 * 64 * 8 * 2
                            + (size_t)NT * HH * 4 * 2;

    int* ws_i   = (int*)d_ws;
    int* counts = ws_i;          // direct: cursor/counts;  fallback: counts
    int* cursor = ws_i + 16;     // fallback cursor
    int* po     = ws_i + 24;     // fallback po

    // ======== direct layout: hdr | srow[segs] | scol[segs] | inv | packW | SQ | xb | tmp
    const int capE = (E + 63) & ~63;
    const int bpt  = capE / 64;
    const size_t segs = (size_t)capE * NT;
    size_t srow_d_off = 256;
    size_t scol_d_off = srow_d_off + segs * 4;
    size_t inv_d_off  = scol_d_off + segs * 4;
    size_t pk_d_off   = (inv_d_off + (size_t)E * 4 + 255) & ~(size_t)255;
    size_t sq_d_off   = (pk_d_off + pack_bytes + 255) & ~(size_t)255;
    size_t xb_d_off   = (sq_d_off + (size_t)Nn * 8 + 255) & ~(size_t)255;
    size_t tmp_d_off  = (xb_d_off + (size_t)xtotal * 2 + 255) & ~(size_t)255;
    size_t direct_end = tmp_d_off + segs * DD * 4;
    const int use_direct = (ws_size >= direct_end) ? 1 : 0;

    if (use_direct) {
        int* srow = (int*)((char*)d_ws + srow_d_off);
        int* scol = (int*)((char*)d_ws + scol_d_off);
        int* inv  = (int*)((char*)d_ws + inv_d_off);
        unsigned short* W1p = (unsigned short*)((char*)d_ws + pk_d_off);
        unsigned short* W2p = W1p + (size_t)NT * 4 * 8 * 64 * 8;
        float* s1g = (float*)(W2p + (size_t)NT * 2 * 64 * 8);
        float* c1g = s1g + NT * HH;
        float2* SQ = (float2*)((char*)d_ws + sq_d_off);
        unsigned short* xb = (unsigned short*)((char*)d_ws + xb_d_off);
        float* tmp = (float*)((char*)d_ws + tmp_d_off);

        hipMemsetAsync(counts, 0, 64, stream);
        const int pt = 50176 + Nn * 16;
        hipLaunchKernelGGL(pack_kernel, dim3((pt + 255) / 256), dim3(256), 0, stream,
                           W1, W2, gamma, beta, b1, x, W1p, W2p, s1g, c1g, xb, SQ, Nn);
        hipLaunchKernelGGL(scatter_direct, dim3((hq + 255) / 256), dim3(256), 0, stream,
                           edge_types, edge_index, counts, srow, scol, inv, E, capE);
        hipLaunchKernelGGL((sheaf_main_full<1>), dim3(NT * bpt), dim3(256), 0, stream,
                           xb, b2, W1p, W2p, s1g, c1g, SQ, counts, counts,
                           (const int*)0, srow, scol, tmp, bpt, capE);
        hipLaunchKernelGGL(permute_kernel, dim3((E + 255) / 256), dim3(256), 0, stream,
                           (const float4*)tmp, inv, (float4*)out, E);
        return;
    }

    // ======== fallback layouts (po-based) ========
    const int cap = capE + 512;
    int* sorted = ws_i + 40;
    int* srow   = sorted + cap;
    int* scol   = srow + cap;
    size_t pk_off = (((size_t)(40 + 3 * (size_t)cap)) * 4 + 255) & ~(size_t)255;
    unsigned short* W1p = (unsigned short*)((char*)d_ws + pk_off);
    unsigned short* W2p = W1p + (size_t)NT * 4 * 8 * 64 * 8;
    float* s1g = (float*)(W2p + (size_t)NT * 2 * 64 * 8);
    float* c1g = s1g + NT * HH;
    size_t sq_off = (pk_off + pack_bytes + 255) & ~(size_t)255;
    float2* SQ = (float2*)((char*)d_ws + sq_off);
    size_t xb_off = (sq_off + (size_t)Nn * 8 + 255) & ~(size_t)255;
    unsigned short* xb = (unsigned short*)((char*)d_ws + xb_off);
    const size_t xb_end = xb_off + (size_t)xtotal * 2;
    const int use_full = (ws_size >= xb_end) ? 1 : 0;

    hipMemsetAsync(counts, 0, 32, stream);
    const int pt = use_full ? (50176 + Nn * 16) : 50176;
    hipLaunchKernelGGL(pack_kernel, dim3((pt + 255) / 256), dim3(256), 0, stream,
                       W1, W2, gamma, beta, b1, x, W1p, W2p, s1g, c1g,
                       xb, SQ, use_full ? Nn : 0);
    hipLaunchKernelGGL(hist_kernel, dim3((hq + 255) / 256), dim3(256), 0, stream,
                       edge_types, counts, E);
    hipLaunchKernelGGL(scan_kernel, dim3(1), dim3(64), 0, stream, counts, po, cursor);
    hipLaunchKernelGGL(scatter_kernel, dim3((hq + 255) / 256), dim3(256), 0, stream,
                       edge_types, edge_index, cursor, sorted, srow, scol, E);

    const int gmain = cap / 64;
    if (use_full)
        hipLaunchKernelGGL((sheaf_main_full<0>), dim3(gmain), dim3(256), 0, stream,
                           xb, b2, W1p, W2p, s1g, c1g, SQ, po, counts,
                           sorted, srow, scol, out, 0, 0);
    else
        hipLaunchKernelGGL(sheaf_main_fb, dim3(gmain), dim3(256), 0, stream,
                           x, b2, W1p, W2p, s1g, c1g, po, counts,
                           sorted, srow, scol, out);
}